// Round 5
// baseline (279.730 us; speedup 1.0000x reference)
//
#include <hip/hip_runtime.h>
#include <stdint.h>

typedef __attribute__((ext_vector_type(8))) short short8;
typedef __attribute__((ext_vector_type(4))) float f32x4;

__device__ __forceinline__ uint32_t f2bf1(float f) {
  union { float f; uint32_t u; } c; c.f = f;
  return (c.u + 0x7FFFu + ((c.u >> 16) & 1u)) >> 16;
}
__device__ __forceinline__ uint32_t pack2bf(float lo, float hi) {
  return f2bf1(lo) | (f2bf1(hi) << 16);
}
__device__ __forceinline__ float bflo(uint32_t u) {
  union { uint32_t u; float f; } c; c.u = u << 16; return c.f;
}
__device__ __forceinline__ float bfhi(uint32_t u) {
  union { uint32_t u; float f; } c; c.u = u & 0xFFFF0000u; return c.f;
}

// ---------------- CSR build: degree count -----------------------------------
__global__ void __launch_bounds__(256) count_kernel(
    const int* __restrict__ dst, uint32_t* __restrict__ deg, int E) {
  int e = blockIdx.x * 256 + threadIdx.x;
  if (e < E) atomicAdd(&deg[dst[e]], 1u);
}

// ---------------- scan stage 1: per-1024-chunk exclusive partials -----------
__global__ void __launch_bounds__(256) scan1_kernel(
    const uint32_t* __restrict__ deg, uint32_t* __restrict__ partial,
    uint32_t* __restrict__ bsum, int N) {
  __shared__ uint32_t sm[256];
  int t = threadIdx.x;
  int base = blockIdx.x * 1024 + t * 4;
  uint32_t d0 = 0, d1 = 0, d2 = 0, d3 = 0;
  if (base + 3 < N) {
    uint4 v = *reinterpret_cast<const uint4*>(deg + base);
    d0 = v.x; d1 = v.y; d2 = v.z; d3 = v.w;
  } else {
    if (base + 0 < N) d0 = deg[base + 0];
    if (base + 1 < N) d1 = deg[base + 1];
    if (base + 2 < N) d2 = deg[base + 2];
    if (base + 3 < N) d3 = deg[base + 3];
  }
  uint32_t s4 = d0 + d1 + d2 + d3;
  sm[t] = s4;
  uint32_t v = s4;
  __syncthreads();
  #pragma unroll
  for (int off = 1; off < 256; off <<= 1) {
    uint32_t u = (t >= off) ? sm[t - off] : 0u;
    __syncthreads();
    v += u;
    sm[t] = v;
    __syncthreads();
  }
  uint32_t ex = v - s4;
  if (base + 0 < N) partial[base + 0] = ex;
  if (base + 1 < N) partial[base + 1] = ex + d0;
  if (base + 2 < N) partial[base + 2] = ex + d0 + d1;
  if (base + 3 < N) partial[base + 3] = ex + d0 + d1 + d2;
  if (t == 255) bsum[blockIdx.x] = v;
}

// ---------------- scan stage 2: exclusive scan of block sums ----------------
__global__ void __launch_bounds__(1024) scan2_kernel(
    const uint32_t* __restrict__ bsum, uint32_t* __restrict__ boff, int nb) {
  __shared__ uint32_t sm[1024];
  int t = threadIdx.x;
  uint32_t s = (t < nb) ? bsum[t] : 0u;
  sm[t] = s;
  uint32_t v = s;
  __syncthreads();
  #pragma unroll
  for (int off = 1; off < 1024; off <<= 1) {
    uint32_t u = (t >= off) ? sm[t - off] : 0u;
    __syncthreads();
    v += u;
    sm[t] = v;
    __syncthreads();
  }
  if (t < nb) boff[t] = v - s;
}

// ---------------- CSR build: fill (src, weight) pairs -----------------------
__global__ void __launch_bounds__(256) fill_kernel(
    const int* __restrict__ src, const int* __restrict__ dst,
    const float* __restrict__ ew, const uint32_t* __restrict__ partial,
    const uint32_t* __restrict__ boff, uint32_t* __restrict__ cursor,
    uint2* __restrict__ pairs, int E) {
  int e = blockIdx.x * 256 + threadIdx.x;
  if (e < E) {
    int d = dst[e];
    uint32_t pos = atomicAdd(&cursor[d], 1u);
    union { float f; uint32_t u; } w; w.f = ew[e];
    pairs[partial[d] + boff[d >> 10] + pos] = make_uint2((uint32_t)src[e], w.u);
  }
}

// ---------------- x (fp32) -> bf16 into cat first halves --------------------
__global__ void __launch_bounds__(256) xconv_kernel(
    const float* __restrict__ x, uint32_t* __restrict__ cat, int N) {
  int n = blockIdx.x * 4 + (threadIdx.x >> 6);
  if (n >= N) return;
  int lane = threadIdx.x & 63;
  float2 xv = reinterpret_cast<const float2*>(x + (size_t)n * 128)[lane];
  cat[(size_t)n * 128 + lane] = pack2bf(xv.x, xv.y);
}

// ---------------- Gather (bf16 rows, 2 edges/iter) + normalize --------------
__global__ void __launch_bounds__(256) gather_kernel(
    const uint2* __restrict__ pairs, const uint32_t* __restrict__ partial,
    const uint32_t* __restrict__ boff, const uint32_t* __restrict__ deg,
    uint32_t* __restrict__ cat, int N) {
  int n = blockIdx.x * 4 + (threadIdx.x >> 6);
  if (n >= N) return;
  int lane = threadIdx.x & 63;
  int half = lane >> 5;
  int sl = lane & 31;
  uint32_t base = partial[n] + boff[n >> 10];
  uint32_t dn = deg[n];
  float a0 = 0.f, a1 = 0.f, a2 = 0.f, a3 = 0.f;
  for (uint32_t k = (uint32_t)half; k < dn; k += 2) {
    uint2 p = pairs[base + k];
    union { uint32_t u; float f; } w; w.u = p.y;
    uint2 v = reinterpret_cast<const uint2*>(cat + (size_t)p.x * 128)[sl];
    a0 += w.f * bflo(v.x);
    a1 += w.f * bfhi(v.x);
    a2 += w.f * bflo(v.y);
    a3 += w.f * bfhi(v.y);
  }
  a0 += __shfl_xor(a0, 32, 64);
  a1 += __shfl_xor(a1, 32, 64);
  a2 += __shfl_xor(a2, 32, 64);
  a3 += __shfl_xor(a3, 32, 64);
  float ss = a0 * a0 + a1 * a1 + a2 * a2 + a3 * a3;
  #pragma unroll
  for (int m = 16; m >= 1; m >>= 1) ss += __shfl_xor(ss, m, 64);
  float scale = 1.0f / fmaxf(sqrtf(ss), 1e-12f);
  if (half == 0) {
    uint2 o;
    o.x = pack2bf(a0 * scale, a1 * scale);
    o.y = pack2bf(a2 * scale, a3 * scale);
    reinterpret_cast<uint2*>(cat + (size_t)n * 128 + 64)[sl] = o;
  }
}

// ---------------- out = normalize(cat @ W^T + b), W staged in LDS -----------
// 512 threads (8 waves); LDS holds bf16 W [128][256] with hw ^= (row&7)<<3
// swizzle. Waves grid-stride over 16-row tiles. B-frag via ds_read_b128.
__global__ void __launch_bounds__(512, 4) gemm_kernel(
    const ushort* __restrict__ cat, const float* __restrict__ W,
    const float* __restrict__ bias, float* __restrict__ out, int N) {
  __shared__ __align__(16) ushort Wl[32768];  // 64 KB
  int t = threadIdx.x;

  // ---- stage W: fp32 -> bf16 into swizzled LDS (4096 16B chunks) ----
  #pragma unroll
  for (int i = 0; i < 8; ++i) {
    int c = t + i * 512;              // chunk id
    int row = c >> 5;                 // W row (0..127)
    const float4* s4 = reinterpret_cast<const float4*>(W + (size_t)row * 256 + (c & 31) * 8);
    float4 f0 = s4[0], f1 = s4[1];
    uint4 pk;
    pk.x = pack2bf(f0.x, f0.y);
    pk.y = pack2bf(f0.z, f0.w);
    pk.z = pack2bf(f1.x, f1.y);
    pk.w = pack2bf(f1.z, f1.w);
    uint32_t hw = (uint32_t)(c * 8) ^ (uint32_t)((row & 7) << 3);
    *reinterpret_cast<uint4*>(&Wl[hw]) = pk;
  }
  __syncthreads();

  int wid = t >> 6;
  int lane = t & 63;
  int r = lane & 15;
  int kg = lane >> 4;

  float bv[8];
  #pragma unroll
  for (int nt = 0; nt < 8; ++nt) bv[nt] = bias[nt * 16 + r];

  int ntiles = N >> 4;
  int gw = blockIdx.x * 8 + wid;
  int nw = gridDim.x * 8;

  for (int tile = gw; tile < ntiles; tile += nw) {
    int node0 = tile * 16;

    short8 a[8];
    const ushort* arow = cat + (size_t)(node0 + r) * 256 + kg * 8;
    #pragma unroll
    for (int ks = 0; ks < 8; ++ks)
      a[ks] = *reinterpret_cast<const short8*>(arow + ks * 32);

    f32x4 acc[8];
    #pragma unroll
    for (int nt = 0; nt < 8; ++nt) acc[nt] = (f32x4){0.f, 0.f, 0.f, 0.f};

    #pragma unroll
    for (int nt = 0; nt < 8; ++nt) {
      uint32_t rowbase = (uint32_t)(nt * 4096 + r * 256);
      #pragma unroll
      for (int ks = 0; ks < 8; ++ks) {
        uint32_t hw = rowbase + (uint32_t)((ks * 32 + kg * 8) ^ ((r & 7) << 3));
        short8 bfrag = *reinterpret_cast<const short8*>(&Wl[hw]);
        acc[nt] = __builtin_amdgcn_mfma_f32_16x16x32_bf16(a[ks], bfrag, acc[nt], 0, 0, 0);
      }
    }

    #pragma unroll
    for (int reg = 0; reg < 4; ++reg) {
      float ss = 0.f;
      #pragma unroll
      for (int nt = 0; nt < 8; ++nt) {
        float v = acc[nt][reg] + bv[nt];
        acc[nt][reg] = v;
        ss += v * v;
      }
      ss += __shfl_xor(ss, 1, 64);
      ss += __shfl_xor(ss, 2, 64);
      ss += __shfl_xor(ss, 4, 64);
      ss += __shfl_xor(ss, 8, 64);
      float scale = 1.0f / fmaxf(sqrtf(ss), 1e-12f);
      float* orow = out + (size_t)(node0 + kg * 4 + reg) * 128;
      #pragma unroll
      for (int nt = 0; nt < 8; ++nt)
        orow[nt * 16 + r] = acc[nt][reg] * scale;
    }
  }
}

extern "C" void kernel_launch(void* const* d_in, const int* in_sizes, int n_in,
                              void* d_out, int out_size, void* d_ws, size_t ws_size,
                              hipStream_t stream) {
  const float* x    = (const float*)d_in[0];
  const int*   ei   = (const int*)d_in[1];   // [2, E]: row0 = src, row1 = dst
  const float* ew   = (const float*)d_in[2];
  const float* W    = (const float*)d_in[3];
  const float* bias = (const float*)d_in[4];
  float* out = (float*)d_out;

  int N = in_sizes[0] / 128;
  int E = in_sizes[1] / 2;
  const int* src = ei;
  const int* dst = ei + E;
  int nb = (N + 1023) / 1024;

  // d_ws: bf16 cat [N][256] (N*128 u32)
  uint32_t* cat = (uint32_t*)d_ws;

  // CSR scratch in d_out (free until gemm overwrites d_out):
  uint32_t* o       = (uint32_t*)d_out;
  uint32_t* deg     = o;
  uint32_t* cursor  = o + N;
  uint32_t* partial = o + 2 * (size_t)N;
  uint32_t* bsum    = o + 3 * (size_t)N;
  uint32_t* boff    = o + 3 * (size_t)N + 1024;
  uint2*    pairs   = (uint2*)(o + 3 * (size_t)N + 2048);

  hipMemsetAsync(deg, 0, 2 * (size_t)N * sizeof(uint32_t), stream);  // deg+cursor
  count_kernel<<<(E + 255) / 256, 256, 0, stream>>>(dst, deg, E);
  xconv_kernel<<<(N + 3) / 4, 256, 0, stream>>>(x, cat, N);
  scan1_kernel<<<nb, 256, 0, stream>>>(deg, partial, bsum, N);
  scan2_kernel<<<1, 1024, 0, stream>>>(bsum, boff, nb);
  fill_kernel<<<(E + 255) / 256, 256, 0, stream>>>(src, dst, ew, partial, boff,
                                                   cursor, pairs, E);
  gather_kernel<<<(N + 3) / 4, 256, 0, stream>>>(pairs, partial, boff, deg, cat, N);
  gemm_kernel<<<512, 512, 0, stream>>>((const ushort*)cat, W, bias, out, N);
}

// Round 6
// 190.822 us; speedup vs baseline: 1.4659x; 1.4659x over previous
//
#include <hip/hip_runtime.h>
#include <stdint.h>

typedef __attribute__((ext_vector_type(8))) short short8;
typedef __attribute__((ext_vector_type(4))) float f32x4;

__device__ __forceinline__ uint32_t f2bf1(float f) {
  union { float f; uint32_t u; } c; c.f = f;
  return (c.u + 0x7FFFu + ((c.u >> 16) & 1u)) >> 16;
}
__device__ __forceinline__ uint32_t pack2bf(float lo, float hi) {
  return f2bf1(lo) | (f2bf1(hi) << 16);
}
__device__ __forceinline__ float bflo(uint32_t u) {
  union { uint32_t u; float f; } c; c.u = u << 16; return c.f;
}
__device__ __forceinline__ float bfhi(uint32_t u) {
  union { uint32_t u; float f; } c; c.u = u & 0xFFFF0000u; return c.f;
}

// ---------------- CSR build: degree count -----------------------------------
__global__ void __launch_bounds__(256) count_kernel(
    const int* __restrict__ dst, uint32_t* __restrict__ deg, int E) {
  int e = blockIdx.x * 256 + threadIdx.x;
  if (e < E) atomicAdd(&deg[dst[e]], 1u);
}

// ---------------- scan stage 1: per-1024-chunk exclusive partials -----------
__global__ void __launch_bounds__(256) scan1_kernel(
    const uint32_t* __restrict__ deg, uint32_t* __restrict__ partial,
    uint32_t* __restrict__ bsum, int N) {
  __shared__ uint32_t sm[256];
  int t = threadIdx.x;
  int base = blockIdx.x * 1024 + t * 4;
  uint32_t d0 = 0, d1 = 0, d2 = 0, d3 = 0;
  if (base + 3 < N) {
    uint4 v = *reinterpret_cast<const uint4*>(deg + base);
    d0 = v.x; d1 = v.y; d2 = v.z; d3 = v.w;
  } else {
    if (base + 0 < N) d0 = deg[base + 0];
    if (base + 1 < N) d1 = deg[base + 1];
    if (base + 2 < N) d2 = deg[base + 2];
    if (base + 3 < N) d3 = deg[base + 3];
  }
  uint32_t s4 = d0 + d1 + d2 + d3;
  sm[t] = s4;
  uint32_t v = s4;
  __syncthreads();
  #pragma unroll
  for (int off = 1; off < 256; off <<= 1) {
    uint32_t u = (t >= off) ? sm[t - off] : 0u;
    __syncthreads();
    v += u;
    sm[t] = v;
    __syncthreads();
  }
  uint32_t ex = v - s4;
  if (base + 0 < N) partial[base + 0] = ex;
  if (base + 1 < N) partial[base + 1] = ex + d0;
  if (base + 2 < N) partial[base + 2] = ex + d0 + d1;
  if (base + 3 < N) partial[base + 3] = ex + d0 + d1 + d2;
  if (t == 255) bsum[blockIdx.x] = v;
}

// ---------------- scan stage 2: exclusive scan of block sums ----------------
__global__ void __launch_bounds__(1024) scan2_kernel(
    const uint32_t* __restrict__ bsum, uint32_t* __restrict__ boff, int nb) {
  __shared__ uint32_t sm[1024];
  int t = threadIdx.x;
  uint32_t s = (t < nb) ? bsum[t] : 0u;
  sm[t] = s;
  uint32_t v = s;
  __syncthreads();
  #pragma unroll
  for (int off = 1; off < 1024; off <<= 1) {
    uint32_t u = (t >= off) ? sm[t - off] : 0u;
    __syncthreads();
    v += u;
    sm[t] = v;
    __syncthreads();
  }
  if (t < nb) boff[t] = v - s;
}

// ---------------- CSR build: fill (src, weight) pairs -----------------------
__global__ void __launch_bounds__(256) fill_kernel(
    const int* __restrict__ src, const int* __restrict__ dst,
    const float* __restrict__ ew, const uint32_t* __restrict__ partial,
    const uint32_t* __restrict__ boff, uint32_t* __restrict__ cursor,
    uint2* __restrict__ pairs, int E) {
  int e = blockIdx.x * 256 + threadIdx.x;
  if (e < E) {
    int d = dst[e];
    uint32_t pos = atomicAdd(&cursor[d], 1u);
    union { float f; uint32_t u; } w; w.f = ew[e];
    pairs[partial[d] + boff[d >> 10] + pos] = make_uint2((uint32_t)src[e], w.u);
  }
}

// ---------------- x (fp32) -> bf16 into cat first halves --------------------
__global__ void __launch_bounds__(256) xconv_kernel(
    const float* __restrict__ x, uint32_t* __restrict__ cat, int N) {
  int n = blockIdx.x * 4 + (threadIdx.x >> 6);
  if (n >= N) return;
  int lane = threadIdx.x & 63;
  float2 xv = reinterpret_cast<const float2*>(x + (size_t)n * 128)[lane];
  cat[(size_t)n * 128 + lane] = pack2bf(xv.x, xv.y);
}

// ---------------- Gather (bf16 rows, 2 edges/iter) + normalize --------------
__global__ void __launch_bounds__(256) gather_kernel(
    const uint2* __restrict__ pairs, const uint32_t* __restrict__ partial,
    const uint32_t* __restrict__ boff, const uint32_t* __restrict__ deg,
    uint32_t* __restrict__ cat, int N) {
  int n = blockIdx.x * 4 + (threadIdx.x >> 6);
  if (n >= N) return;
  int lane = threadIdx.x & 63;
  int half = lane >> 5;
  int sl = lane & 31;
  uint32_t base = partial[n] + boff[n >> 10];
  uint32_t dn = deg[n];
  float a0 = 0.f, a1 = 0.f, a2 = 0.f, a3 = 0.f;
  for (uint32_t k = (uint32_t)half; k < dn; k += 2) {
    uint2 p = pairs[base + k];
    union { uint32_t u; float f; } w; w.u = p.y;
    uint2 v = reinterpret_cast<const uint2*>(cat + (size_t)p.x * 128)[sl];
    a0 += w.f * bflo(v.x);
    a1 += w.f * bfhi(v.x);
    a2 += w.f * bflo(v.y);
    a3 += w.f * bfhi(v.y);
  }
  a0 += __shfl_xor(a0, 32, 64);
  a1 += __shfl_xor(a1, 32, 64);
  a2 += __shfl_xor(a2, 32, 64);
  a3 += __shfl_xor(a3, 32, 64);
  float ss = a0 * a0 + a1 * a1 + a2 * a2 + a3 * a3;
  #pragma unroll
  for (int m = 16; m >= 1; m >>= 1) ss += __shfl_xor(ss, m, 64);
  float scale = 1.0f / fmaxf(sqrtf(ss), 1e-12f);
  if (half == 0) {
    uint2 o;
    o.x = pack2bf(a0 * scale, a1 * scale);
    o.y = pack2bf(a2 * scale, a3 * scale);
    reinterpret_cast<uint2*>(cat + (size_t)n * 128 + 64)[sl] = o;
  }
}

// ---------------- W (fp32 [128][256]) -> bf16 -------------------------------
__global__ void __launch_bounds__(256) wconv_kernel(
    const float* __restrict__ W, uint32_t* __restrict__ Wb, int n2) {
  int i = blockIdx.x * 256 + threadIdx.x;
  if (i < n2) {
    float2 wv = reinterpret_cast<const float2*>(W)[i];
    Wb[i] = pack2bf(wv.x, wv.y);
  }
}

// ---------------- out = normalize(cat @ W^T + b) ----------------------------
// One wave per 32-node tile (two 16-row subtiles sharing each B-frag load).
// MFMA 16x16x32 bf16; K=256 (8 steps), Ncols=128 (8 tiles of 16).
__global__ void __launch_bounds__(256) gemm_kernel(
    const ushort* __restrict__ cat, const ushort* __restrict__ Wb,
    const float* __restrict__ bias, float* __restrict__ out, int N) {
  int wid = threadIdx.x >> 6;
  int lane = threadIdx.x & 63;
  int node0 = (blockIdx.x * 4 + wid) * 32;
  if (node0 >= N) return;
  int r = lane & 15;
  int kg = lane >> 4;

  short8 a0[8], a1[8];
  const ushort* arow0 = cat + (size_t)(node0 + r) * 256 + kg * 8;
  const ushort* arow1 = arow0 + 16 * 256;
  #pragma unroll
  for (int ks = 0; ks < 8; ++ks) {
    a0[ks] = *reinterpret_cast<const short8*>(arow0 + ks * 32);
    a1[ks] = *reinterpret_cast<const short8*>(arow1 + ks * 32);
  }

  f32x4 acc0[8], acc1[8];
  #pragma unroll
  for (int nt = 0; nt < 8; ++nt) {
    acc0[nt] = (f32x4){0.f, 0.f, 0.f, 0.f};
    acc1[nt] = (f32x4){0.f, 0.f, 0.f, 0.f};
  }

  const ushort* wbase = Wb + kg * 8;
  #pragma unroll
  for (int nt = 0; nt < 8; ++nt) {
    const ushort* wrow = wbase + (size_t)(nt * 16 + r) * 256;
    #pragma unroll
    for (int ks = 0; ks < 8; ++ks) {
      short8 bfrag = *reinterpret_cast<const short8*>(wrow + ks * 32);
      acc0[nt] = __builtin_amdgcn_mfma_f32_16x16x32_bf16(a0[ks], bfrag, acc0[nt], 0, 0, 0);
      acc1[nt] = __builtin_amdgcn_mfma_f32_16x16x32_bf16(a1[ks], bfrag, acc1[nt], 0, 0, 0);
    }
  }

  float bv[8];
  #pragma unroll
  for (int nt = 0; nt < 8; ++nt) bv[nt] = bias[nt * 16 + r];

  #pragma unroll
  for (int st = 0; st < 2; ++st) {
    f32x4* acc = st ? acc1 : acc0;
    int nodeb = node0 + st * 16;
    #pragma unroll
    for (int reg = 0; reg < 4; ++reg) {
      float ss = 0.f;
      #pragma unroll
      for (int nt = 0; nt < 8; ++nt) {
        float v = acc[nt][reg] + bv[nt];
        acc[nt][reg] = v;
        ss += v * v;
      }
      ss += __shfl_xor(ss, 1, 64);
      ss += __shfl_xor(ss, 2, 64);
      ss += __shfl_xor(ss, 4, 64);
      ss += __shfl_xor(ss, 8, 64);
      float scale = 1.0f / fmaxf(sqrtf(ss), 1e-12f);
      float* orow = out + (size_t)(nodeb + kg * 4 + reg) * 128;
      #pragma unroll
      for (int nt = 0; nt < 8; ++nt)
        orow[nt * 16 + r] = acc[nt][reg] * scale;
    }
  }
}

extern "C" void kernel_launch(void* const* d_in, const int* in_sizes, int n_in,
                              void* d_out, int out_size, void* d_ws, size_t ws_size,
                              hipStream_t stream) {
  const float* x    = (const float*)d_in[0];
  const int*   ei   = (const int*)d_in[1];   // [2, E]: row0 = src, row1 = dst
  const float* ew   = (const float*)d_in[2];
  const float* W    = (const float*)d_in[3];
  const float* bias = (const float*)d_in[4];
  float* out = (float*)d_out;

  int N = in_sizes[0] / 128;
  int E = in_sizes[1] / 2;
  const int* src = ei;
  const int* dst = ei + E;
  int nb = (N + 1023) / 1024;

  // d_ws: bf16 cat [N][256] (N*128 u32), then bf16 W (16384 u32)
  uint32_t* cat = (uint32_t*)d_ws;
  uint32_t* Wb  = cat + (size_t)N * 128;

  // CSR scratch in d_out (free until gemm overwrites d_out):
  uint32_t* o       = (uint32_t*)d_out;
  uint32_t* deg     = o;
  uint32_t* cursor  = o + N;
  uint32_t* partial = o + 2 * (size_t)N;
  uint32_t* bsum    = o + 3 * (size_t)N;
  uint32_t* boff    = o + 3 * (size_t)N + 1024;
  uint2*    pairs   = (uint2*)(o + 3 * (size_t)N + 2048);

  hipMemsetAsync(deg, 0, 2 * (size_t)N * sizeof(uint32_t), stream);  // deg+cursor
  count_kernel<<<(E + 255) / 256, 256, 0, stream>>>(dst, deg, E);
  xconv_kernel<<<(N + 3) / 4, 256, 0, stream>>>(x, cat, N);
  wconv_kernel<<<(16384 + 255) / 256, 256, 0, stream>>>(W, Wb, 16384);
  scan1_kernel<<<nb, 256, 0, stream>>>(deg, partial, bsum, N);
  scan2_kernel<<<1, 1024, 0, stream>>>(bsum, boff, nb);
  fill_kernel<<<(E + 255) / 256, 256, 0, stream>>>(src, dst, ew, partial, boff,
                                                   cursor, pairs, E);
  gather_kernel<<<(N + 3) / 4, 256, 0, stream>>>(pairs, partial, boff, deg, cat, N);
  int ntiles32 = (N + 31) / 32;
  gemm_kernel<<<(ntiles32 + 3) / 4, 256, 0, stream>>>(
      (const ushort*)cat, (const ushort*)Wb, bias, out, N);
}

// Round 7
// 171.340 us; speedup vs baseline: 1.6326x; 1.1137x over previous
//
#include <hip/hip_runtime.h>
#include <stdint.h>

typedef __attribute__((ext_vector_type(8))) short short8;
typedef __attribute__((ext_vector_type(4))) float f32x4;

__device__ __forceinline__ uint32_t f2bf1(float f) {
  union { float f; uint32_t u; } c; c.f = f;
  return (c.u + 0x7FFFu + ((c.u >> 16) & 1u)) >> 16;
}
__device__ __forceinline__ uint32_t pack2bf(float lo, float hi) {
  return f2bf1(lo) | (f2bf1(hi) << 16);
}
__device__ __forceinline__ float bflo(uint32_t u) {
  union { uint32_t u; float f; } c; c.u = u << 16; return c.f;
}
__device__ __forceinline__ float bfhi(uint32_t u) {
  union { uint32_t u; float f; } c; c.u = u & 0xFFFF0000u; return c.f;
}

// ------- prep: count (deg atomics) + xconv (x->bf16 cat) + wconv (W->bf16) --
// block ranges: [0,cB) count | [cB,cB+xB) xconv | [cB+xB, cB+xB+64) wconv
__global__ void __launch_bounds__(256) prep_kernel(
    const int* __restrict__ dst, uint32_t* __restrict__ deg,
    const float* __restrict__ x, uint32_t* __restrict__ cat,
    const float* __restrict__ W, uint32_t* __restrict__ Wb,
    int E, int N, int cB, int xB) {
  int b = blockIdx.x;
  if (b < cB) {
    int e = b * 256 + threadIdx.x;
    if (e < E) atomicAdd(&deg[dst[e]], 1u);
  } else if (b < cB + xB) {
    int n = (b - cB) * 4 + (threadIdx.x >> 6);
    if (n >= N) return;
    int lane = threadIdx.x & 63;
    float2 xv = reinterpret_cast<const float2*>(x + (size_t)n * 128)[lane];
    cat[(size_t)n * 128 + lane] = pack2bf(xv.x, xv.y);
  } else {
    int i = (b - cB - xB) * 256 + threadIdx.x;  // packs 2 floats of W
    if (i < 16384) {
      float2 wv = reinterpret_cast<const float2*>(W)[i];
      Wb[i] = pack2bf(wv.x, wv.y);
    }
  }
}

// ---------------- scan stage 1: per-1024-chunk exclusive partials -----------
__global__ void __launch_bounds__(256) scan1_kernel(
    const uint32_t* __restrict__ deg, uint32_t* __restrict__ partial,
    uint32_t* __restrict__ bsum, int N) {
  __shared__ uint32_t sm[256];
  int t = threadIdx.x;
  int base = blockIdx.x * 1024 + t * 4;
  uint32_t d0 = 0, d1 = 0, d2 = 0, d3 = 0;
  if (base + 3 < N) {
    uint4 v = *reinterpret_cast<const uint4*>(deg + base);
    d0 = v.x; d1 = v.y; d2 = v.z; d3 = v.w;
  } else {
    if (base + 0 < N) d0 = deg[base + 0];
    if (base + 1 < N) d1 = deg[base + 1];
    if (base + 2 < N) d2 = deg[base + 2];
    if (base + 3 < N) d3 = deg[base + 3];
  }
  uint32_t s4 = d0 + d1 + d2 + d3;
  sm[t] = s4;
  uint32_t v = s4;
  __syncthreads();
  #pragma unroll
  for (int off = 1; off < 256; off <<= 1) {
    uint32_t u = (t >= off) ? sm[t - off] : 0u;
    __syncthreads();
    v += u;
    sm[t] = v;
    __syncthreads();
  }
  uint32_t ex = v - s4;
  if (base + 0 < N) partial[base + 0] = ex;
  if (base + 1 < N) partial[base + 1] = ex + d0;
  if (base + 2 < N) partial[base + 2] = ex + d0 + d1;
  if (base + 3 < N) partial[base + 3] = ex + d0 + d1 + d2;
  if (t == 255) bsum[blockIdx.x] = v;
}

// ---------------- scan stage 2: exclusive scan of block sums ----------------
__global__ void __launch_bounds__(1024) scan2_kernel(
    const uint32_t* __restrict__ bsum, uint32_t* __restrict__ boff, int nb) {
  __shared__ uint32_t sm[1024];
  int t = threadIdx.x;
  uint32_t s = (t < nb) ? bsum[t] : 0u;
  sm[t] = s;
  uint32_t v = s;
  __syncthreads();
  #pragma unroll
  for (int off = 1; off < 1024; off <<= 1) {
    uint32_t u = (t >= off) ? sm[t - off] : 0u;
    __syncthreads();
    v += u;
    sm[t] = v;
    __syncthreads();
  }
  if (t < nb) boff[t] = v - s;
}

// ---------------- CSR build: fill (src, weight) pairs -----------------------
__global__ void __launch_bounds__(256) fill_kernel(
    const int* __restrict__ src, const int* __restrict__ dst,
    const float* __restrict__ ew, const uint32_t* __restrict__ partial,
    const uint32_t* __restrict__ boff, uint32_t* __restrict__ cursor,
    uint2* __restrict__ pairs, int E) {
  int e = blockIdx.x * 256 + threadIdx.x;
  if (e < E) {
    int d = dst[e];
    uint32_t pos = atomicAdd(&cursor[d], 1u);
    union { float f; uint32_t u; } w; w.f = ew[e];
    pairs[partial[d] + boff[d >> 10] + pos] = make_uint2((uint32_t)src[e], w.u);
  }
}

// ---------------- Gather (bf16 rows, 4 edges/iter) + normalize --------------
// Pairs prefetched (one per lane); quarter-wave (16 lanes) per edge, each
// lane covers 8 elems via one uint4 (16B) load => 256B coalesced per edge.
__global__ void __launch_bounds__(256) gather_kernel(
    const uint2* __restrict__ pairs, const uint32_t* __restrict__ partial,
    const uint32_t* __restrict__ boff, const uint32_t* __restrict__ deg,
    uint32_t* __restrict__ cat, int N) {
  int n = blockIdx.x * 4 + (threadIdx.x >> 6);
  if (n >= N) return;
  int lane = threadIdx.x & 63;
  int sg = lane >> 4;   // edge slot within iteration
  int sl = lane & 15;   // element slot: elems 8*sl .. 8*sl+7
  uint32_t base = partial[n] + boff[n >> 10];
  int dn = (int)deg[n];

  uint2 mp = (lane < dn) ? pairs[base + lane] : make_uint2(0u, 0u);

  float a[8] = {0.f, 0.f, 0.f, 0.f, 0.f, 0.f, 0.f, 0.f};
  int iters = (dn + 3) >> 2;
  for (int i = 0; i < iters; ++i) {
    int k = i * 4 + sg;
    uint32_t su = (uint32_t)__shfl((int)mp.x, k, 64);
    uint32_t wu = (uint32_t)__shfl((int)mp.y, k, 64);
    if (k < dn) {
      union { uint32_t u; float f; } w; w.u = wu;
      uint4 v = reinterpret_cast<const uint4*>(cat + (size_t)su * 128)[sl];
      a[0] += w.f * bflo(v.x); a[1] += w.f * bfhi(v.x);
      a[2] += w.f * bflo(v.y); a[3] += w.f * bfhi(v.y);
      a[4] += w.f * bflo(v.z); a[5] += w.f * bfhi(v.z);
      a[6] += w.f * bflo(v.w); a[7] += w.f * bfhi(v.w);
    }
  }
  // correctness tail for deg > 64 (statistically never taken here)
  for (int k = 64 + sg; k < dn; k += 4) {
    uint2 p = pairs[base + k];
    union { uint32_t u; float f; } w; w.u = p.y;
    uint4 v = reinterpret_cast<const uint4*>(cat + (size_t)p.x * 128)[sl];
    a[0] += w.f * bflo(v.x); a[1] += w.f * bfhi(v.x);
    a[2] += w.f * bflo(v.y); a[3] += w.f * bfhi(v.y);
    a[4] += w.f * bflo(v.z); a[5] += w.f * bfhi(v.z);
    a[6] += w.f * bflo(v.w); a[7] += w.f * bfhi(v.w);
  }

  #pragma unroll
  for (int j = 0; j < 8; ++j) {
    a[j] += __shfl_xor(a[j], 16, 64);
    a[j] += __shfl_xor(a[j], 32, 64);
  }
  float ss = 0.f;
  #pragma unroll
  for (int j = 0; j < 8; ++j) ss += a[j] * a[j];
  ss += __shfl_xor(ss, 1, 64);
  ss += __shfl_xor(ss, 2, 64);
  ss += __shfl_xor(ss, 4, 64);
  ss += __shfl_xor(ss, 8, 64);
  float scale = 1.0f / fmaxf(sqrtf(ss), 1e-12f);
  if (lane < 16) {
    uint4 o;
    o.x = pack2bf(a[0] * scale, a[1] * scale);
    o.y = pack2bf(a[2] * scale, a[3] * scale);
    o.z = pack2bf(a[4] * scale, a[5] * scale);
    o.w = pack2bf(a[6] * scale, a[7] * scale);
    reinterpret_cast<uint4*>(cat + (size_t)n * 128 + 64)[sl] = o;
  }
}

// ---------------- out = normalize(cat @ W^T + b) ----------------------------
// One wave per 32-node tile (two 16-row subtiles sharing each B-frag load).
__global__ void __launch_bounds__(256) gemm_kernel(
    const ushort* __restrict__ cat, const ushort* __restrict__ Wb,
    const float* __restrict__ bias, float* __restrict__ out, int N) {
  int wid = threadIdx.x >> 6;
  int lane = threadIdx.x & 63;
  int node0 = (blockIdx.x * 4 + wid) * 32;
  if (node0 >= N) return;
  int r = lane & 15;
  int kg = lane >> 4;

  short8 a0[8], a1[8];
  const ushort* arow0 = cat + (size_t)(node0 + r) * 256 + kg * 8;
  const ushort* arow1 = arow0 + 16 * 256;
  #pragma unroll
  for (int ks = 0; ks < 8; ++ks) {
    a0[ks] = *reinterpret_cast<const short8*>(arow0 + ks * 32);
    a1[ks] = *reinterpret_cast<const short8*>(arow1 + ks * 32);
  }

  f32x4 acc0[8], acc1[8];
  #pragma unroll
  for (int nt = 0; nt < 8; ++nt) {
    acc0[nt] = (f32x4){0.f, 0.f, 0.f, 0.f};
    acc1[nt] = (f32x4){0.f, 0.f, 0.f, 0.f};
  }

  const ushort* wbase = Wb + kg * 8;
  #pragma unroll
  for (int nt = 0; nt < 8; ++nt) {
    const ushort* wrow = wbase + (size_t)(nt * 16 + r) * 256;
    #pragma unroll
    for (int ks = 0; ks < 8; ++ks) {
      short8 bfrag = *reinterpret_cast<const short8*>(wrow + ks * 32);
      acc0[nt] = __builtin_amdgcn_mfma_f32_16x16x32_bf16(a0[ks], bfrag, acc0[nt], 0, 0, 0);
      acc1[nt] = __builtin_amdgcn_mfma_f32_16x16x32_bf16(a1[ks], bfrag, acc1[nt], 0, 0, 0);
    }
  }

  float bv[8];
  #pragma unroll
  for (int nt = 0; nt < 8; ++nt) bv[nt] = bias[nt * 16 + r];

  #pragma unroll
  for (int st = 0; st < 2; ++st) {
    f32x4* acc = st ? acc1 : acc0;
    int nodeb = node0 + st * 16;
    #pragma unroll
    for (int reg = 0; reg < 4; ++reg) {
      float ss = 0.f;
      #pragma unroll
      for (int nt = 0; nt < 8; ++nt) {
        float v = acc[nt][reg] + bv[nt];
        acc[nt][reg] = v;
        ss += v * v;
      }
      ss += __shfl_xor(ss, 1, 64);
      ss += __shfl_xor(ss, 2, 64);
      ss += __shfl_xor(ss, 4, 64);
      ss += __shfl_xor(ss, 8, 64);
      float scale = 1.0f / fmaxf(sqrtf(ss), 1e-12f);
      float* orow = out + (size_t)(nodeb + kg * 4 + reg) * 128;
      #pragma unroll
      for (int nt = 0; nt < 8; ++nt)
        orow[nt * 16 + r] = acc[nt][reg] * scale;
    }
  }
}

extern "C" void kernel_launch(void* const* d_in, const int* in_sizes, int n_in,
                              void* d_out, int out_size, void* d_ws, size_t ws_size,
                              hipStream_t stream) {
  const float* x    = (const float*)d_in[0];
  const int*   ei   = (const int*)d_in[1];   // [2, E]: row0 = src, row1 = dst
  const float* ew   = (const float*)d_in[2];
  const float* W    = (const float*)d_in[3];
  const float* bias = (const float*)d_in[4];
  float* out = (float*)d_out;

  int N = in_sizes[0] / 128;
  int E = in_sizes[1] / 2;
  const int* src = ei;
  const int* dst = ei + E;
  int nb = (N + 1023) / 1024;

  // d_ws: bf16 cat [N][256] (N*128 u32), then bf16 W (16384 u32)
  uint32_t* cat = (uint32_t*)d_ws;
  uint32_t* Wb  = cat + (size_t)N * 128;

  // CSR scratch in d_out (free until gemm overwrites d_out):
  uint32_t* o       = (uint32_t*)d_out;
  uint32_t* deg     = o;
  uint32_t* cursor  = o + N;
  uint32_t* partial = o + 2 * (size_t)N;
  uint32_t* bsum    = o + 3 * (size_t)N;
  uint32_t* boff    = o + 3 * (size_t)N + 1024;
  uint2*    pairs   = (uint2*)(o + 3 * (size_t)N + 2048);

  int cB = (E + 255) / 256;
  int xB = (N + 3) / 4;
  hipMemsetAsync(deg, 0, 2 * (size_t)N * sizeof(uint32_t), stream);  // deg+cursor
  prep_kernel<<<cB + xB + 64, 256, 0, stream>>>(dst, deg, x, cat, W, Wb,
                                                E, N, cB, xB);
  scan1_kernel<<<nb, 256, 0, stream>>>(deg, partial, bsum, N);
  scan2_kernel<<<1, 1024, 0, stream>>>(bsum, boff, nb);
  fill_kernel<<<(E + 255) / 256, 256, 0, stream>>>(src, dst, ew, partial, boff,
                                                   cursor, pairs, E);
  gather_kernel<<<(N + 3) / 4, 256, 0, stream>>>(pairs, partial, boff, deg, cat, N);
  int ntiles32 = (N + 31) / 32;
  gemm_kernel<<<(ntiles32 + 3) / 4, 256, 0, stream>>>(
      (const ushort*)cat, (const ushort*)Wb, bias, out, N);
}

// Round 8
// 147.275 us; speedup vs baseline: 1.8994x; 1.1634x over previous
//
#include <hip/hip_runtime.h>
#include <stdint.h>

typedef __attribute__((ext_vector_type(8))) short short8;
typedef __attribute__((ext_vector_type(4))) float f32x4;

__device__ __forceinline__ uint32_t f2bf1(float f) {
  union { float f; uint32_t u; } c; c.f = f;
  return (c.u + 0x7FFFu + ((c.u >> 16) & 1u)) >> 16;
}
__device__ __forceinline__ uint32_t pack2bf(float lo, float hi) {
  return f2bf1(lo) | (f2bf1(hi) << 16);
}
__device__ __forceinline__ float bflo(uint32_t u) {
  union { uint32_t u; float f; } c; c.u = u << 16; return c.f;
}
__device__ __forceinline__ float bfhi(uint32_t u) {
  union { uint32_t u; float f; } c; c.u = u & 0xFFFF0000u; return c.f;
}

// ------- prep: count+pos (deg atomics) + xconv (x->bf16) + wconv (W->bf16) --
// block ranges: [0,cB) count | [cB,cB+xB) xconv | [cB+xB, cB+xB+64) wconv
__global__ void __launch_bounds__(256) prep_kernel(
    const int* __restrict__ dst, uint32_t* __restrict__ deg,
    uint32_t* __restrict__ pos,
    const float* __restrict__ x, uint32_t* __restrict__ cat,
    const float* __restrict__ W, uint32_t* __restrict__ Wb,
    int E, int N, int cB, int xB) {
  int b = blockIdx.x;
  if (b < cB) {
    int e = b * 256 + threadIdx.x;
    if (e < E) pos[e] = atomicAdd(&deg[dst[e]], 1u);
  } else if (b < cB + xB) {
    int n = (b - cB) * 4 + (threadIdx.x >> 6);
    if (n >= N) return;
    int lane = threadIdx.x & 63;
    float2 xv = reinterpret_cast<const float2*>(x + (size_t)n * 128)[lane];
    cat[(size_t)n * 128 + lane] = pack2bf(xv.x, xv.y);
  } else {
    int i = (b - cB - xB) * 256 + threadIdx.x;  // packs 2 floats of W
    if (i < 16384) {
      float2 wv = reinterpret_cast<const float2*>(W)[i];
      Wb[i] = pack2bf(wv.x, wv.y);
    }
  }
}

// ---------------- scan stage 1: per-1024-chunk exclusive partials -----------
__global__ void __launch_bounds__(256) scan1_kernel(
    const uint32_t* __restrict__ deg, uint32_t* __restrict__ partial,
    uint32_t* __restrict__ bsum, int N) {
  __shared__ uint32_t sm[256];
  int t = threadIdx.x;
  int base = blockIdx.x * 1024 + t * 4;
  uint32_t d0 = 0, d1 = 0, d2 = 0, d3 = 0;
  if (base + 3 < N) {
    uint4 v = *reinterpret_cast<const uint4*>(deg + base);
    d0 = v.x; d1 = v.y; d2 = v.z; d3 = v.w;
  } else {
    if (base + 0 < N) d0 = deg[base + 0];
    if (base + 1 < N) d1 = deg[base + 1];
    if (base + 2 < N) d2 = deg[base + 2];
    if (base + 3 < N) d3 = deg[base + 3];
  }
  uint32_t s4 = d0 + d1 + d2 + d3;
  sm[t] = s4;
  uint32_t v = s4;
  __syncthreads();
  #pragma unroll
  for (int off = 1; off < 256; off <<= 1) {
    uint32_t u = (t >= off) ? sm[t - off] : 0u;
    __syncthreads();
    v += u;
    sm[t] = v;
    __syncthreads();
  }
  uint32_t ex = v - s4;
  if (base + 0 < N) partial[base + 0] = ex;
  if (base + 1 < N) partial[base + 1] = ex + d0;
  if (base + 2 < N) partial[base + 2] = ex + d0 + d1;
  if (base + 3 < N) partial[base + 3] = ex + d0 + d1 + d2;
  if (t == 255) bsum[blockIdx.x] = v;
}

// ---------------- scan stage 2: exclusive scan of block sums ----------------
__global__ void __launch_bounds__(1024) scan2_kernel(
    const uint32_t* __restrict__ bsum, uint32_t* __restrict__ boff, int nb) {
  __shared__ uint32_t sm[1024];
  int t = threadIdx.x;
  uint32_t s = (t < nb) ? bsum[t] : 0u;
  sm[t] = s;
  uint32_t v = s;
  __syncthreads();
  #pragma unroll
  for (int off = 1; off < 1024; off <<= 1) {
    uint32_t u = (t >= off) ? sm[t - off] : 0u;
    __syncthreads();
    v += u;
    sm[t] = v;
    __syncthreads();
  }
  if (t < nb) boff[t] = v - s;
}

// ---------------- CSR fill: no atomics (pos precomputed) --------------------
__global__ void __launch_bounds__(256) fill_kernel(
    const int* __restrict__ src, const int* __restrict__ dst,
    const float* __restrict__ ew, const uint32_t* __restrict__ partial,
    const uint32_t* __restrict__ boff, const uint32_t* __restrict__ pos,
    uint2* __restrict__ pairs, int E) {
  int e = blockIdx.x * 256 + threadIdx.x;
  if (e < E) {
    int d = dst[e];
    union { float f; uint32_t u; } w; w.f = ew[e];
    pairs[partial[d] + boff[d >> 10] + pos[e]] = make_uint2((uint32_t)src[e], w.u);
  }
}

// ---------------- Gather (bf16 rows, 4 edges/iter) + normalize --------------
__global__ void __launch_bounds__(256) gather_kernel(
    const uint2* __restrict__ pairs, const uint32_t* __restrict__ partial,
    const uint32_t* __restrict__ boff, const uint32_t* __restrict__ deg,
    uint32_t* __restrict__ cat, int N) {
  int n = blockIdx.x * 4 + (threadIdx.x >> 6);
  if (n >= N) return;
  int lane = threadIdx.x & 63;
  int sg = lane >> 4;   // edge slot within iteration
  int sl = lane & 15;   // element slot: elems 8*sl .. 8*sl+7
  uint32_t base = partial[n] + boff[n >> 10];
  int dn = (int)deg[n];

  uint2 mp = (lane < dn) ? pairs[base + lane] : make_uint2(0u, 0u);

  float a[8] = {0.f, 0.f, 0.f, 0.f, 0.f, 0.f, 0.f, 0.f};
  int iters = (dn + 3) >> 2;
  for (int i = 0; i < iters; ++i) {
    int k = i * 4 + sg;
    uint32_t su = (uint32_t)__shfl((int)mp.x, k, 64);
    uint32_t wu = (uint32_t)__shfl((int)mp.y, k, 64);
    if (k < dn) {
      union { uint32_t u; float f; } w; w.u = wu;
      uint4 v = reinterpret_cast<const uint4*>(cat + (size_t)su * 128)[sl];
      a[0] += w.f * bflo(v.x); a[1] += w.f * bfhi(v.x);
      a[2] += w.f * bflo(v.y); a[3] += w.f * bfhi(v.y);
      a[4] += w.f * bflo(v.z); a[5] += w.f * bfhi(v.z);
      a[6] += w.f * bflo(v.w); a[7] += w.f * bfhi(v.w);
    }
  }
  // correctness tail for deg > 64 (statistically never taken here)
  for (int k = 64 + sg; k < dn; k += 4) {
    uint2 p = pairs[base + k];
    union { uint32_t u; float f; } w; w.u = p.y;
    uint4 v = reinterpret_cast<const uint4*>(cat + (size_t)p.x * 128)[sl];
    a[0] += w.f * bflo(v.x); a[1] += w.f * bfhi(v.x);
    a[2] += w.f * bflo(v.y); a[3] += w.f * bfhi(v.y);
    a[4] += w.f * bflo(v.z); a[5] += w.f * bfhi(v.z);
    a[6] += w.f * bflo(v.w); a[7] += w.f * bfhi(v.w);
  }

  #pragma unroll
  for (int j = 0; j < 8; ++j) {
    a[j] += __shfl_xor(a[j], 16, 64);
    a[j] += __shfl_xor(a[j], 32, 64);
  }
  float ss = 0.f;
  #pragma unroll
  for (int j = 0; j < 8; ++j) ss += a[j] * a[j];
  ss += __shfl_xor(ss, 1, 64);
  ss += __shfl_xor(ss, 2, 64);
  ss += __shfl_xor(ss, 4, 64);
  ss += __shfl_xor(ss, 8, 64);
  float scale = 1.0f / fmaxf(sqrtf(ss), 1e-12f);
  if (lane < 16) {
    uint4 o;
    o.x = pack2bf(a[0] * scale, a[1] * scale);
    o.y = pack2bf(a[2] * scale, a[3] * scale);
    o.z = pack2bf(a[4] * scale, a[5] * scale);
    o.w = pack2bf(a[6] * scale, a[7] * scale);
    reinterpret_cast<uint4*>(cat + (size_t)n * 128 + 64)[sl] = o;
  }
}

// ---------------- out = normalize(cat @ W^T + b) ----------------------------
// One wave per 32-node tile (two 16-row subtiles sharing each B-frag load).
__global__ void __launch_bounds__(256) gemm_kernel(
    const ushort* __restrict__ cat, const ushort* __restrict__ Wb,
    const float* __restrict__ bias, float* __restrict__ out, int N) {
  int wid = threadIdx.x >> 6;
  int lane = threadIdx.x & 63;
  int node0 = (blockIdx.x * 4 + wid) * 32;
  if (node0 >= N) return;
  int r = lane & 15;
  int kg = lane >> 4;

  short8 a0[8], a1[8];
  const ushort* arow0 = cat + (size_t)(node0 + r) * 256 + kg * 8;
  const ushort* arow1 = arow0 + 16 * 256;
  #pragma unroll
  for (int ks = 0; ks < 8; ++ks) {
    a0[ks] = *reinterpret_cast<const short8*>(arow0 + ks * 32);
    a1[ks] = *reinterpret_cast<const short8*>(arow1 + ks * 32);
  }

  f32x4 acc0[8], acc1[8];
  #pragma unroll
  for (int nt = 0; nt < 8; ++nt) {
    acc0[nt] = (f32x4){0.f, 0.f, 0.f, 0.f};
    acc1[nt] = (f32x4){0.f, 0.f, 0.f, 0.f};
  }

  const ushort* wbase = Wb + kg * 8;
  #pragma unroll
  for (int nt = 0; nt < 8; ++nt) {
    const ushort* wrow = wbase + (size_t)(nt * 16 + r) * 256;
    #pragma unroll
    for (int ks = 0; ks < 8; ++ks) {
      short8 bfrag = *reinterpret_cast<const short8*>(wrow + ks * 32);
      acc0[nt] = __builtin_amdgcn_mfma_f32_16x16x32_bf16(a0[ks], bfrag, acc0[nt], 0, 0, 0);
      acc1[nt] = __builtin_amdgcn_mfma_f32_16x16x32_bf16(a1[ks], bfrag, acc1[nt], 0, 0, 0);
    }
  }

  float bv[8];
  #pragma unroll
  for (int nt = 0; nt < 8; ++nt) bv[nt] = bias[nt * 16 + r];

  #pragma unroll
  for (int st = 0; st < 2; ++st) {
    f32x4* acc = st ? acc1 : acc0;
    int nodeb = node0 + st * 16;
    #pragma unroll
    for (int reg = 0; reg < 4; ++reg) {
      float ss = 0.f;
      #pragma unroll
      for (int nt = 0; nt < 8; ++nt) {
        float v = acc[nt][reg] + bv[nt];
        acc[nt][reg] = v;
        ss += v * v;
      }
      ss += __shfl_xor(ss, 1, 64);
      ss += __shfl_xor(ss, 2, 64);
      ss += __shfl_xor(ss, 4, 64);
      ss += __shfl_xor(ss, 8, 64);
      float scale = 1.0f / fmaxf(sqrtf(ss), 1e-12f);
      float* orow = out + (size_t)(nodeb + kg * 4 + reg) * 128;
      #pragma unroll
      for (int nt = 0; nt < 8; ++nt)
        orow[nt * 16 + r] = acc[nt][reg] * scale;
    }
  }
}

extern "C" void kernel_launch(void* const* d_in, const int* in_sizes, int n_in,
                              void* d_out, int out_size, void* d_ws, size_t ws_size,
                              hipStream_t stream) {
  const float* x    = (const float*)d_in[0];
  const int*   ei   = (const int*)d_in[1];   // [2, E]: row0 = src, row1 = dst
  const float* ew   = (const float*)d_in[2];
  const float* W    = (const float*)d_in[3];
  const float* bias = (const float*)d_in[4];
  float* out = (float*)d_out;

  int N = in_sizes[0] / 128;
  int E = in_sizes[1] / 2;
  const int* src = ei;
  const int* dst = ei + E;
  int nb = (N + 1023) / 1024;

  // d_ws: bf16 cat [N][256] (N*128 u32), then bf16 W (16384 u32)
  uint32_t* cat = (uint32_t*)d_ws;
  uint32_t* Wb  = cat + (size_t)N * 128;

  // CSR scratch in d_out (free until gemm overwrites d_out):
  // deg[N], partial[N], bsum[1024], boff[1024], pairs[E](uint2), pos[E]
  uint32_t* o       = (uint32_t*)d_out;
  uint32_t* deg     = o;
  uint32_t* partial = o + N;
  uint32_t* bsum    = o + 2 * (size_t)N;
  uint32_t* boff    = o + 2 * (size_t)N + 1024;
  uint2*    pairs   = (uint2*)(o + 2 * (size_t)N + 2048);
  uint32_t* pos     = o + 2 * (size_t)N + 2048 + 2 * (size_t)E;

  int cB = (E + 255) / 256;
  int xB = (N + 3) / 4;
  hipMemsetAsync(deg, 0, (size_t)N * sizeof(uint32_t), stream);
  prep_kernel<<<cB + xB + 64, 256, 0, stream>>>(dst, deg, pos, x, cat, W, Wb,
                                                E, N, cB, xB);
  scan1_kernel<<<nb, 256, 0, stream>>>(deg, partial, bsum, N);
  scan2_kernel<<<1, 1024, 0, stream>>>(bsum, boff, nb);
  fill_kernel<<<(E + 255) / 256, 256, 0, stream>>>(src, dst, ew, partial, boff,
                                                   pos, pairs, E);
  gather_kernel<<<(N + 3) / 4, 256, 0, stream>>>(pairs, partial, boff, deg, cat, N);
  int ntiles32 = (N + 31) / 32;
  gemm_kernel<<<(ntiles32 + 3) / 4, 256, 0, stream>>>(
      (const ushort*)cat, (const ushort*)Wb, bias, out, N);
}